// Round 1
// baseline (2938.210 us; speedup 1.0000x reference)
//
#include <hip/hip_runtime.h>
#include <math.h>

// Problem constants
#define NTOT 32768   // T*B
#define CIN  201
#define S    67      // keypoints (seq len)
#define E    8
#define H    2
#define DH   4
#define L    12
#define FF   16
#define OUTC 128
#define KF   (S*E)   // 536
#define EPB  3       // batch elements per block (3*67 = 201 rows <= 256 lanes)

__device__ __forceinline__ void layernorm8(float* xr, const float* __restrict__ gg,
                                           const float* __restrict__ bb) {
    float m = 0.f;
    #pragma unroll
    for (int e = 0; e < E; ++e) m += xr[e];
    m *= 0.125f;
    float v = 0.f;
    #pragma unroll
    for (int e = 0; e < E; ++e) { float d = xr[e] - m; v += d * d; }
    v *= 0.125f;
    float rs = rsqrtf(v + 1e-5f);
    #pragma unroll
    for (int e = 0; e < E; ++e) xr[e] = (xr[e] - m) * rs * gg[e] + bb[e];
}

__global__ __launch_bounds__(256, 2)
void enc_kernel(const float* __restrict__ pose,
                const float* __restrict__ ew,  const float* __restrict__ ebias,
                const float* __restrict__ ipw, const float* __restrict__ ipb,
                const float* __restrict__ aow, const float* __restrict__ aob,
                const float* __restrict__ f1w, const float* __restrict__ f1b,
                const float* __restrict__ f2w, const float* __restrict__ f2b,
                const float* __restrict__ g1,  const float* __restrict__ b1,
                const float* __restrict__ g2,  const float* __restrict__ b2,
                float* __restrict__ xf)
{
    __shared__ float4 Ks[EPB * H * S];
    __shared__ float4 Vs[EPB * H * S];

    const int lid = threadIdx.x;
    const int g   = lid / S;            // element within block (3 valid)
    const int s   = lid - g * S;        // keypoint row
    const int n   = blockIdx.x * EPB + g;
    const bool active = (g < EPB) && (n < NTOT);

    // ---- embed: x[s,e] = pose[n, 3s..3s+2] @ ew[e,:].T + eb[e] ----
    float xr[E];
    if (active) {
        const float* p = pose + (size_t)n * CIN + 3 * s;
        float r0 = p[0], r1 = p[1], r2 = p[2];
        #pragma unroll
        for (int e = 0; e < E; ++e)
            xr[e] = ebias[e] + r0 * ew[e*3+0] + r1 * ew[e*3+1] + r2 * ew[e*3+2];
    }

    for (int l = 0; l < L; ++l) {
        const float* wq = ipw + l * (3*E*E);
        const float* bq = ipb + l * (3*E);
        float q[E];
        if (active) {
            #pragma unroll
            for (int j = 0; j < E; ++j) {          // q rows 0..7
                float a = bq[j];
                #pragma unroll
                for (int e = 0; e < E; ++e) a += xr[e] * wq[j*E + e];
                q[j] = a;
            }
            float kv[2*E];
            #pragma unroll
            for (int j = 0; j < 2*E; ++j) {        // k rows 8..15, v rows 16..23
                float a = bq[E + j];
                #pragma unroll
                for (int e = 0; e < E; ++e) a += xr[e] * wq[(E + j)*E + e];
                kv[j] = a;
            }
            Ks[(g*H + 0)*S + s] = make_float4(kv[0],  kv[1],  kv[2],  kv[3]);
            Ks[(g*H + 1)*S + s] = make_float4(kv[4],  kv[5],  kv[6],  kv[7]);
            Vs[(g*H + 0)*S + s] = make_float4(kv[8],  kv[9],  kv[10], kv[11]);
            Vs[(g*H + 1)*S + s] = make_float4(kv[12], kv[13], kv[14], kv[15]);
        }
        __syncthreads();

        float o[E];
        if (active) {
            #pragma unroll
            for (int h = 0; h < H; ++h) {
                const float4* K4 = &Ks[(g*H + h) * S];
                const float4* V4 = &Vs[(g*H + h) * S];
                const float q0 = q[h*4+0], q1 = q[h*4+1], q2 = q[h*4+2], q3 = q[h*4+3];
                float sc[S];
                #pragma unroll
                for (int t = 0; t < S; ++t) {
                    float4 k4 = K4[t];
                    sc[t] = 0.5f * (q0*k4.x + q1*k4.y + q2*k4.z + q3*k4.w);  // 1/sqrt(4)
                }
                float m = sc[0];
                #pragma unroll
                for (int t = 1; t < S; ++t) m = fmaxf(m, sc[t]);
                float lsum = 0.f;
                #pragma unroll
                for (int t = 0; t < S; ++t) { sc[t] = __expf(sc[t] - m); lsum += sc[t]; }
                float o0 = 0.f, o1 = 0.f, o2 = 0.f, o3 = 0.f;
                #pragma unroll
                for (int t = 0; t < S; ++t) {
                    float4 v4 = V4[t];
                    o0 += sc[t]*v4.x; o1 += sc[t]*v4.y; o2 += sc[t]*v4.z; o3 += sc[t]*v4.w;
                }
                float inv = 1.0f / lsum;
                o[h*4+0] = o0*inv; o[h*4+1] = o1*inv; o[h*4+2] = o2*inv; o[h*4+3] = o3*inv;
            }
            // attn_out + residual + LN1
            const float* wa = aow + l*E*E;
            const float* ba = aob + l*E;
            float tmp[E];
            #pragma unroll
            for (int e = 0; e < E; ++e) {
                float a = ba[e];
                #pragma unroll
                for (int e2 = 0; e2 < E; ++e2) a += o[e2] * wa[e*E + e2];
                tmp[e] = a;
            }
            #pragma unroll
            for (int e = 0; e < E; ++e) xr[e] += tmp[e];
            layernorm8(xr, g1 + l*E, b1 + l*E);

            // FF: relu(x @ f1.T + b1) @ f2.T + b2, residual, LN2
            float t1[FF];
            #pragma unroll
            for (int f = 0; f < FF; ++f) {
                float a = f1b[l*FF + f];
                #pragma unroll
                for (int e = 0; e < E; ++e) a += xr[e] * f1w[l*FF*E + f*E + e];
                t1[f] = fmaxf(a, 0.f);
            }
            #pragma unroll
            for (int e = 0; e < E; ++e) {
                float a = f2b[l*E + e];
                #pragma unroll
                for (int f = 0; f < FF; ++f) a += t1[f] * f2w[l*E*FF + e*FF + f];
                xr[e] += a;
            }
            layernorm8(xr, g2 + l*E, b2 + l*E);
        }
        __syncthreads();   // protect K/V before next layer overwrites
    }

    if (active) {
        float4* o4 = (float4*)(xf + (size_t)n * KF + s * E);
        o4[0] = make_float4(xr[0], xr[1], xr[2], xr[3]);
        o4[1] = make_float4(xr[4], xr[5], xr[6], xr[7]);
    }
}

// out = tanh(Xf[32768,536] @ W.T[536,128] + b)
__global__ __launch_bounds__(256, 2)
void out_kernel(const float* __restrict__ xf, const float* __restrict__ ow,
                const float* __restrict__ ob, float* __restrict__ out)
{
    __shared__ float Xs[64][69];   // 64 rows x 67-k chunk, padded stride 69
    const int lid = threadIdx.x;
    const int tx  = lid & 31;      // col group: cols tx*4 .. tx*4+3
    const int ty  = lid >> 5;      // row group: rows ty*8 .. ty*8+7
    const int n0  = blockIdx.x * 64;

    float acc[8][4];
    #pragma unroll
    for (int i = 0; i < 8; ++i)
        #pragma unroll
        for (int j = 0; j < 4; ++j) acc[i][j] = 0.f;

    for (int kc = 0; kc < 8; ++kc) {       // 536 = 8 * 67
        const int kb = kc * S;
        __syncthreads();
        for (int i = lid; i < 64 * S; i += 256) {
            int r = i / S, k = i - r * S;
            Xs[r][k] = xf[(size_t)(n0 + r) * KF + kb + k];
        }
        __syncthreads();
        for (int k = 0; k < S; ++k) {
            float w0 = ow[(tx*4+0)*KF + kb + k];
            float w1 = ow[(tx*4+1)*KF + kb + k];
            float w2 = ow[(tx*4+2)*KF + kb + k];
            float w3 = ow[(tx*4+3)*KF + kb + k];
            #pragma unroll
            for (int i = 0; i < 8; ++i) {
                float x = Xs[ty*8 + i][k];
                acc[i][0] += x*w0; acc[i][1] += x*w1; acc[i][2] += x*w2; acc[i][3] += x*w3;
            }
        }
    }

    const float b0 = ob[tx*4+0], b1 = ob[tx*4+1], b2 = ob[tx*4+2], b3 = ob[tx*4+3];
    #pragma unroll
    for (int i = 0; i < 8; ++i) {
        int r = n0 + ty*8 + i;
        float4 v;
        v.x = tanhf(acc[i][0] + b0);
        v.y = tanhf(acc[i][1] + b1);
        v.z = tanhf(acc[i][2] + b2);
        v.w = tanhf(acc[i][3] + b3);
        *(float4*)(out + (size_t)r * OUTC + tx*4) = v;
    }
}

extern "C" void kernel_launch(void* const* d_in, const int* in_sizes, int n_in,
                              void* d_out, int out_size, void* d_ws, size_t ws_size,
                              hipStream_t stream) {
    (void)in_sizes; (void)n_in; (void)out_size; (void)ws_size;
    const float* pose = (const float*)d_in[0];
    const float* ew   = (const float*)d_in[1];
    const float* eb   = (const float*)d_in[2];
    const float* ipw  = (const float*)d_in[3];
    const float* ipb  = (const float*)d_in[4];
    const float* aow  = (const float*)d_in[5];
    const float* aob  = (const float*)d_in[6];
    const float* f1w  = (const float*)d_in[7];
    const float* f1b  = (const float*)d_in[8];
    const float* f2w  = (const float*)d_in[9];
    const float* f2b  = (const float*)d_in[10];
    const float* g1   = (const float*)d_in[11];
    const float* b1   = (const float*)d_in[12];
    const float* g2   = (const float*)d_in[13];
    const float* b2   = (const float*)d_in[14];
    const float* ow   = (const float*)d_in[15];
    const float* ob   = (const float*)d_in[16];

    float* xf = (float*)d_ws;   // 32768 * 536 * 4 B = 70.25 MB scratch

    const int grid1 = (NTOT + EPB - 1) / EPB;   // 10923
    enc_kernel<<<grid1, 256, 0, stream>>>(pose, ew, eb, ipw, ipb, aow, aob,
                                          f1w, f1b, f2w, f2b, g1, b1, g2, b2, xf);
    out_kernel<<<NTOT / 64, 256, 0, stream>>>(xf, ow, ob, (float*)d_out);
}

// Round 2
// 1712.933 us; speedup vs baseline: 1.7153x; 1.7153x over previous
//
#include <hip/hip_runtime.h>
#include <math.h>

// Problem constants
#define NTOT 32768   // T*B
#define CIN  201
#define S    67      // keypoints (seq len)
#define E    8
#define H    2
#define L    12
#define FF   16
#define OUTC 128
#define KF   536     // S*E
#define EPB  7       // batch elements per block (7*67 = 469 of 512 lanes = 91.6% fill)
#define THREADS 512

#if __has_builtin(__builtin_amdgcn_exp2f)
#define EXP2F(x) __builtin_amdgcn_exp2f(x)
#else
#define EXP2F(x) exp2f(x)
#endif
#if __has_builtin(__builtin_amdgcn_rcpf)
#define RCPF(x) __builtin_amdgcn_rcpf(x)
#else
#define RCPF(x) (1.0f/(x))
#endif
#if __has_builtin(__builtin_amdgcn_rsqf)
#define RSQF(x) __builtin_amdgcn_rsqf(x)
#else
#define RSQF(x) rsqrtf(x)
#endif

// 0.5 (=1/sqrt(DH)) * log2(e): fold softmax scale + exp->exp2 conversion into q
#define QSCALE 0.7213475204444817f

__device__ __forceinline__ void layernorm8(float* xr, const float* __restrict__ gg,
                                           const float* __restrict__ bb) {
    float m = 0.f;
    #pragma unroll
    for (int e = 0; e < E; ++e) m += xr[e];
    m *= 0.125f;
    float v = 0.f;
    #pragma unroll
    for (int e = 0; e < E; ++e) { float d = xr[e] - m; v += d * d; }
    v *= 0.125f;
    float rs = RSQF(v + 1e-5f);
    #pragma unroll
    for (int e = 0; e < E; ++e) xr[e] = (xr[e] - m) * rs * gg[e] + bb[e];
}

__global__ __launch_bounds__(THREADS, 4)
void enc_kernel(const float* __restrict__ pose,
                const float* __restrict__ ew,  const float* __restrict__ ebias,
                const float* __restrict__ ipw, const float* __restrict__ ipb,
                const float* __restrict__ aow, const float* __restrict__ aob,
                const float* __restrict__ f1w, const float* __restrict__ f1b,
                const float* __restrict__ f2w, const float* __restrict__ f2b,
                const float* __restrict__ g1,  const float* __restrict__ b1,
                const float* __restrict__ g2,  const float* __restrict__ b2,
                float* __restrict__ xf)
{
    __shared__ float4 Ks[EPB * H * S];
    __shared__ float4 Vs[EPB * H * S];

    const int lid = threadIdx.x;
    const int g   = lid / S;            // element within block (0..6 valid)
    const int s   = lid - g * S;        // keypoint row
    const int n   = blockIdx.x * EPB + g;
    const bool active = (g < EPB) && (n < NTOT);

    // ---- embed: x[s,e] = pose[n, 3s..3s+2] @ ew[e,:].T + eb[e] ----
    float xr[E];
    if (active) {
        const float* p = pose + (size_t)n * CIN + 3 * s;
        float r0 = p[0], r1 = p[1], r2 = p[2];
        #pragma unroll
        for (int e = 0; e < E; ++e)
            xr[e] = ebias[e] + r0 * ew[e*3+0] + r1 * ew[e*3+1] + r2 * ew[e*3+2];
    }

    #pragma unroll 1
    for (int l = 0; l < L; ++l) {
        const float* wq = ipw + l * (3*E*E);
        const float* bq = ipb + l * (3*E);
        float qs[E];
        if (active) {
            #pragma unroll
            for (int j = 0; j < E; ++j) {          // q rows 0..7 (pre-scaled)
                float a = bq[j];
                #pragma unroll
                for (int e = 0; e < E; ++e) a += xr[e] * wq[j*E + e];
                qs[j] = a * QSCALE;
            }
            float kv[2*E];
            #pragma unroll
            for (int j = 0; j < 2*E; ++j) {        // k rows 8..15, v rows 16..23
                float a = bq[E + j];
                #pragma unroll
                for (int e = 0; e < E; ++e) a += xr[e] * wq[(E + j)*E + e];
                kv[j] = a;
            }
            Ks[(g*H + 0)*S + s] = make_float4(kv[0],  kv[1],  kv[2],  kv[3]);
            Ks[(g*H + 1)*S + s] = make_float4(kv[4],  kv[5],  kv[6],  kv[7]);
            Vs[(g*H + 0)*S + s] = make_float4(kv[8],  kv[9],  kv[10], kv[11]);
            Vs[(g*H + 1)*S + s] = make_float4(kv[12], kv[13], kv[14], kv[15]);
        }
        __syncthreads();

        if (active) {
            float o[E];
            // ---- fused single-pass softmax-attention (no max-sub: |score|<~2,
            // softmax is shift-invariant; exp folded to v_exp via pre-scaled q) ----
            #pragma unroll
            for (int h = 0; h < H; ++h) {
                const float4* K4 = &Ks[(g*H + h) * S];
                const float4* V4 = &Vs[(g*H + h) * S];
                const float q0 = qs[h*4+0], q1 = qs[h*4+1], q2 = qs[h*4+2], q3 = qs[h*4+3];
                float lsum = 0.f;
                float o0 = 0.f, o1 = 0.f, o2 = 0.f, o3 = 0.f;
                #pragma unroll
                for (int t = 0; t < S; ++t) {
                    float4 k4 = K4[t];
                    float4 v4 = V4[t];
                    float sc = q0*k4.x + q1*k4.y + q2*k4.z + q3*k4.w;
                    float e  = EXP2F(sc);
                    lsum += e;
                    o0 += e*v4.x; o1 += e*v4.y; o2 += e*v4.z; o3 += e*v4.w;
                }
                float inv = RCPF(lsum);
                o[h*4+0] = o0*inv; o[h*4+1] = o1*inv; o[h*4+2] = o2*inv; o[h*4+3] = o3*inv;
            }
            // attn_out + residual + LN1
            const float* wa = aow + l*E*E;
            const float* ba = aob + l*E;
            float tmp[E];
            #pragma unroll
            for (int e = 0; e < E; ++e) {
                float a = ba[e];
                #pragma unroll
                for (int e2 = 0; e2 < E; ++e2) a += o[e2] * wa[e*E + e2];
                tmp[e] = a;
            }
            #pragma unroll
            for (int e = 0; e < E; ++e) xr[e] += tmp[e];
            layernorm8(xr, g1 + l*E, b1 + l*E);

            // FF: relu(x @ f1.T + b1) @ f2.T + b2, residual, LN2
            float t1[FF];
            #pragma unroll
            for (int f = 0; f < FF; ++f) {
                float a = f1b[l*FF + f];
                #pragma unroll
                for (int e = 0; e < E; ++e) a += xr[e] * f1w[l*FF*E + f*E + e];
                t1[f] = fmaxf(a, 0.f);
            }
            #pragma unroll
            for (int e = 0; e < E; ++e) {
                float a = f2b[l*E + e];
                #pragma unroll
                for (int f = 0; f < FF; ++f) a += t1[f] * f2w[l*E*FF + e*FF + f];
                xr[e] += a;
            }
            layernorm8(xr, g2 + l*E, b2 + l*E);
        }
        __syncthreads();   // protect K/V before next layer overwrites
    }

    if (active) {
        float4* o4 = (float4*)(xf + (size_t)n * KF + s * E);
        o4[0] = make_float4(xr[0], xr[1], xr[2], xr[3]);
        o4[1] = make_float4(xr[4], xr[5], xr[6], xr[7]);
    }
}

// wt[k][c] = ow[c][k]  (268 KB, makes out_kernel W loads coalesced float4)
__global__ void tr_kernel(const float* __restrict__ ow, float* __restrict__ wt)
{
    int i = blockIdx.x * 256 + threadIdx.x;
    if (i < OUTC * KF) {
        int c = i / KF, k = i - c * KF;   // read coalesced
        wt[k * OUTC + c] = ow[i];
    }
}

// out = tanh(Xf[32768,536] @ Wt[536,128] + b)
__global__ __launch_bounds__(256, 4)
void out_kernel(const float* __restrict__ xf, const float* __restrict__ wt,
                const float* __restrict__ ob, float* __restrict__ out)
{
    __shared__ float Xs[32][68];   // 32 rows; pad 68 keeps rows 16B-aligned
    const int lid = threadIdx.x;
    const int tx  = lid & 31;      // cols tx*4 .. tx*4+3
    const int ty  = lid >> 5;      // rows ty*4 .. ty*4+3
    const int n0  = blockIdx.x * 32;

    float acc[4][4] = {};

    #pragma unroll 1
    for (int kc = 0; kc < 9; ++kc) {       // 8 chunks of 64 + 1 of 24
        const int kb = kc * 64;
        const int kw = (kc < 8) ? 64 : 24;
        __syncthreads();
        const int nvec = 32 * (kw >> 2);
        for (int i = lid; i < nvec; i += 256) {
            int r = i / (kw >> 2), kq = i - r * (kw >> 2);
            *(float4*)&Xs[r][kq*4] =
                *(const float4*)&xf[(size_t)(n0 + r) * KF + kb + kq*4];
        }
        __syncthreads();
        #pragma unroll 4
        for (int k = 0; k < kw; ++k) {
            float4 w4 = *(const float4*)&wt[(size_t)(kb + k) * OUTC + tx*4];
            #pragma unroll
            for (int i = 0; i < 4; ++i) {
                float x = Xs[ty*4 + i][k];
                acc[i][0] += x*w4.x; acc[i][1] += x*w4.y;
                acc[i][2] += x*w4.z; acc[i][3] += x*w4.w;
            }
        }
    }

    const float4 bb = *(const float4*)&ob[tx*4];
    #pragma unroll
    for (int i = 0; i < 4; ++i) {
        int r = n0 + ty*4 + i;
        float4 v;
        v.x = tanhf(acc[i][0] + bb.x);
        v.y = tanhf(acc[i][1] + bb.y);
        v.z = tanhf(acc[i][2] + bb.z);
        v.w = tanhf(acc[i][3] + bb.w);
        *(float4*)(out + (size_t)r * OUTC + tx*4) = v;
    }
}

extern "C" void kernel_launch(void* const* d_in, const int* in_sizes, int n_in,
                              void* d_out, int out_size, void* d_ws, size_t ws_size,
                              hipStream_t stream) {
    (void)in_sizes; (void)n_in; (void)out_size; (void)ws_size;
    const float* pose = (const float*)d_in[0];
    const float* ew   = (const float*)d_in[1];
    const float* eb   = (const float*)d_in[2];
    const float* ipw  = (const float*)d_in[3];
    const float* ipb  = (const float*)d_in[4];
    const float* aow  = (const float*)d_in[5];
    const float* aob  = (const float*)d_in[6];
    const float* f1w  = (const float*)d_in[7];
    const float* f1b  = (const float*)d_in[8];
    const float* f2w  = (const float*)d_in[9];
    const float* f2b  = (const float*)d_in[10];
    const float* g1   = (const float*)d_in[11];
    const float* b1   = (const float*)d_in[12];
    const float* g2   = (const float*)d_in[13];
    const float* b2   = (const float*)d_in[14];
    const float* ow   = (const float*)d_in[15];
    const float* ob   = (const float*)d_in[16];

    float* xf = (float*)d_ws;                       // 70.25 MB
    float* wt = (float*)d_ws + (size_t)NTOT * KF;   // + 268 KB

    const int grid1 = (NTOT + EPB - 1) / EPB;       // 4682
    enc_kernel<<<grid1, THREADS, 0, stream>>>(pose, ew, eb, ipw, ipb, aow, aob,
                                              f1w, f1b, f2w, f2b, g1, b1, g2, b2, xf);
    tr_kernel<<<(OUTC*KF + 255)/256, 256, 0, stream>>>(ow, wt);
    out_kernel<<<NTOT / 32, 256, 0, stream>>>(xf, wt, ob, (float*)d_out);
}